// Round 8
// baseline (99.383 us; speedup 1.0000x reference)
//
#include <hip/hip_runtime.h>

#define NEG_SLOPE 0.2f

// ws layout (in floats)
#define OFF_U   0        // 3 layers * 256 (u_src[128] | u_dst[128])
#define OFF_WT  1024     // 3 * 16384 (W transposed: WT[d*128+e] = W[e*128+d])
#define OFF_XT  50176    // x~ : [b][p][d] = 64*16*128 floats

__device__ __forceinline__ float lrelu(float z) { return z >= 0.f ? z : NEG_SLOPE * z; }

// ---------------------------------------------------------------------------
// Setup: grid 48 = 3 layers x 16 sub-blocks. LDS-tiled coalesced transpose;
// sub==0 block also computes u vectors (u = a @ W).  [verbatim from round 6]
__global__ __launch_bounds__(256) void setup_kernel(
    const float* __restrict__ W0, const float* __restrict__ as0, const float* __restrict__ ad0,
    const float* __restrict__ W1, const float* __restrict__ as1, const float* __restrict__ ad1,
    const float* __restrict__ W2, const float* __restrict__ as2, const float* __restrict__ ad2,
    float* __restrict__ ws) {
  __shared__ float tile[8][132];
  const int bid = blockIdx.x;
  const int l = bid >> 4, sub = bid & 15;
  const int tid = threadIdx.x;
  const float* W = (l == 0) ? W0 : (l == 1) ? W1 : W2;
  float* WT = ws + OFF_WT + l * 16384;
  const int e0 = sub * 8;

#pragma unroll
  for (int i = 0; i < 4; ++i) {     // read 8 rows of W, coalesced
    const int idx = i * 256 + tid;
    tile[idx >> 7][idx & 127] = W[(e0 + (idx >> 7)) * 128 + (idx & 127)];
  }
  __syncthreads();
#pragma unroll
  for (int i = 0; i < 4; ++i) {     // write transposed
    const int idx = i * 256 + tid;
    const int d = idx >> 3, j = idx & 7;
    WT[d * 128 + e0 + j] = tile[j][d];
  }
  if (sub == 0) {
    const float* av = (tid < 128) ? ((l == 0) ? as0 : (l == 1) ? as1 : as2)
                                  : ((l == 0) ? ad0 : (l == 1) ? ad1 : ad2);
    const int d = tid & 127;
    float acc = 0.f;
#pragma unroll 8
    for (int e = 0; e < 128; ++e) acc += av[e] * W[e * 128 + d];
    ws[OFF_U + l * 256 + tid] = acc;
  }
}

// ---------------------------------------------------------------------------
// Layer 0: one block per (b, patch p). 256 threads. NO x staging: phase 1
// streams x (s,t dots), tiny attention, phase 3 re-reads x (L3-hot) for the
// weighted column-sum. LDS ~16 KB; launch_bounds(256,6) -> 6 blocks/CU.
__global__ __launch_bounds__(256, 6) void l0_kernel(
    const float* __restrict__ x, const int* __restrict__ lengths,
    const float* __restrict__ uvec, float* __restrict__ xt_out) {
  __shared__ float u_sh[256];
  __shared__ float stp[4][256];
  __shared__ float ttp[4][256];
  __shared__ float sA[256], tA[256];
  __shared__ float am1[256], asf[256], ap1[256];
  __shared__ float w_sh[256];
  __shared__ float xrow[128];

  const int tid  = threadIdx.x;
  const int bid  = blockIdx.x;
  const int b = bid >> 4;
  const int p = bid & 15;
  const int lane = tid & 63;
  const int wave = tid >> 6;

  u_sh[tid] = uvec[tid];
  __syncthreads();

  // ---- phase 1: streaming s,t dot products (no stores of x) ----
  const float* xb = x + ((size_t)b * 128) * 4096 + p * 256;
  float s0 = 0.f, s1 = 0.f, s2 = 0.f, s3 = 0.f;
  float t0 = 0.f, t1 = 0.f, t2 = 0.f, t3 = 0.f;
#pragma unroll 8
  for (int it = 0; it < 32; ++it) {
    const int d = it * 4 + wave;
    const float4 v = *(const float4*)(xb + (size_t)d * 4096 + lane * 4);
    const float us = u_sh[d], ud = u_sh[128 + d];
    s0 += v.x * us; s1 += v.y * us; s2 += v.z * us; s3 += v.w * us;
    t0 += v.x * ud; t1 += v.y * ud; t2 += v.z * ud; t3 += v.w * ud;
  }
  *(float4*)(&stp[wave][lane * 4]) = make_float4(s0, s1, s2, s3);
  *(float4*)(&ttp[wave][lane * 4]) = make_float4(t0, t1, t2, t3);
  __syncthreads();

  {   // combine s,t across the 4 waves
    const int n = tid;
    sA[n] = stp[0][n] + stp[1][n] + stp[2][n] + stp[3][n];
    tA[n] = ttp[0][n] + ttp[1][n] + ttp[2][n] + ttp[3][n];
  }
  __syncthreads();

  const int len = lengths[b];

  {   // attention per dst j (sources j-1, j, j+1); fold dst validity  [r2-verified]
    const int j = tid;
    const float tj = tA[j];
    const float ls = lrelu(sA[j] + tj);
    const float lm = (j > 0)   ? lrelu(sA[j - 1] + tj) : -1e30f;
    const float lp = (j < 255) ? lrelu(sA[j + 1] + tj) : -1e30f;
    const float mx = fmaxf(ls, fmaxf(lm, lp));
    const float em = (j > 0)   ? __expf(lm - mx) : 0.f;
    const float es = __expf(ls - mx);
    const float ep = (j < 255) ? __expf(lp - mx) : 0.f;
    const float vj = ((p * 256 + j) < len) ? 1.f : 0.f;
    const float sc = vj / (em + es + ep);
    am1[j] = em * sc; asf[j] = es * sc; ap1[j] = ep * sc;
  }
  __syncthreads();

  {   // source weights w[n]  [r2-verified]
    const int n = tid;
    float w = asf[n];
    if (n < 255) w += am1[n + 1];
    if (n > 0)   w += ap1[n - 1];
    w_sh[n] = w;
  }
  __syncthreads();

  // ---- phase 3: re-read x (L3-hot), weighted column-sum via shfl ----
  {
    const float4 wv = *(const float4*)(&w_sh[lane * 4]);
#pragma unroll 4
    for (int it = 0; it < 32; ++it) {
      const int d = it * 4 + wave;
      const float4 v = *(const float4*)(xb + (size_t)d * 4096 + lane * 4);
      float a = v.x * wv.x + v.y * wv.y + v.z * wv.z + v.w * wv.w;
      a += __shfl_xor(a, 1);  a += __shfl_xor(a, 2);  a += __shfl_xor(a, 4);
      a += __shfl_xor(a, 8);  a += __shfl_xor(a, 16); a += __shfl_xor(a, 32);
      if (lane == 0) xrow[d] = a;
    }
  }
  __syncthreads();

  if (tid < 128)
    xt_out[((size_t)b * 16 + p) * 128 + tid] = xrow[tid];
}

// ---------------------------------------------------------------------------
// Fused: feat GEMV (W0) + layer1 + layer2. One block per b, 256 threads.
// [round 6 verbatim except xt load layout]
__global__ __launch_bounds__(256) void l12_kernel(
    const float* __restrict__ xtp, const int* __restrict__ lengths,
    const float* __restrict__ ws,
    const float* __restrict__ b0, const float* __restrict__ b1,
    const float* __restrict__ b2, float* __restrict__ out) {
  __shared__ float xt[16][128];
  __shared__ float pr[2][16][128];
  __shared__ float feat[16][128];
  __shared__ float spt[2][16][16];
  __shared__ float s1[16], t1[16], am[16], asf[16], ap[16], w16[16];
  __shared__ float rc_sh[16];
  __shared__ float x1t[4][128];
  __shared__ float h1[4][128];

  const int tid = threadIdx.x;
  const int b = blockIdx.x;
  const float* WT0 = ws + OFF_WT;
  const float* WT1 = ws + OFF_WT + 16384;
  const float* WT2 = ws + OFF_WT + 32768;
  const float* u1  = ws + OFF_U + 256;
  const int len = lengths[b];

#pragma unroll
  for (int i = 0; i < 8; ++i) {   // load x~ per patch
    const int pp = i * 2 + (tid >> 7);
    const int d = tid & 127;
    xt[pp][d] = xtp[((size_t)b * 16 + pp) * 128 + d];
  }
  if (tid < 16) {
    const int rem = len - tid * 256;
    const int cnt = rem < 0 ? 0 : (rem > 256 ? 256 : rem);
    rc_sh[tid] = cnt > 0 ? 1.f / (float)cnt : 0.f;
  }
  __syncthreads();

  {   // feat[p][e] = sum_d xt[p][d] * WT0[d*128+e]
    const int e = tid & 127, dhalf = tid >> 7;
    float acc[16];
#pragma unroll
    for (int q = 0; q < 16; ++q) acc[q] = 0.f;
#pragma unroll 4
    for (int k = 0; k < 64; ++k) {
      const int d = dhalf * 64 + k;
      const float wv = WT0[d * 128 + e];
#pragma unroll
      for (int q = 0; q < 16; ++q) acc[q] += xt[q][d] * wv;
    }
#pragma unroll
    for (int q = 0; q < 16; ++q) pr[dhalf][q][e] = acc[q];
  }
  __syncthreads();
  {
    const int e = tid & 127, ph = tid >> 7;
    const float bb = b0[e];
#pragma unroll
    for (int i = 0; i < 8; ++i) {
      const int q = ph * 8 + i;
      const float rcv = rc_sh[q];
      const float f = (pr[0][q][e] + pr[1][q][e]) * rcv + bb;
      feat[q][e] = (rcv == 0.f) ? 0.f : f;
    }
  }
  __syncthreads();

  {   // layer-1 s,t partials
    const int q = tid >> 4, sl = tid & 15;
    float ps = 0.f, pt = 0.f;
#pragma unroll
    for (int k = 0; k < 8; ++k) {
      const int e = sl * 8 + k;
      const float f = feat[q][e];
      ps += f * u1[e];
      pt += f * u1[128 + e];
    }
    spt[0][q][sl] = ps; spt[1][q][sl] = pt;
  }
  __syncthreads();
  if (tid < 32) {
    const int q = tid >> 4, pp = tid & 15;
    float a = 0.f;
#pragma unroll
    for (int i = 0; i < 16; ++i) a += spt[q][pp][i];
    if (q == 0) s1[pp] = a; else t1[pp] = a;
  }
  __syncthreads();
  if (tid < 16) {   // attention within groups of 4
    const int jl = tid & 3;
    const float tj = t1[tid];
    const float ls = lrelu(s1[tid] + tj);
    const float lm = (jl > 0) ? lrelu(s1[tid - 1] + tj) : -1e30f;
    const float lp = (jl < 3) ? lrelu(s1[tid + 1] + tj) : -1e30f;
    const float mx = fmaxf(ls, fmaxf(lm, lp));
    const float em = (jl > 0) ? __expf(lm - mx) : 0.f;
    const float es = __expf(ls - mx);
    const float ep = (jl < 3) ? __expf(lp - mx) : 0.f;
    const float sc = 1.f / (em + es + ep);
    am[tid] = em * sc; asf[tid] = es * sc; ap[tid] = ep * sc;
  }
  __syncthreads();
  if (tid < 16) {
    const int jl = tid & 3;
    float w = asf[tid];
    if (jl < 3) w += am[tid + 1];
    if (jl > 0) w += ap[tid - 1];
    w16[tid] = w;
  }
  __syncthreads();
#pragma unroll
  for (int r = 0; r < 2; ++r) {   // x1t[g][d] = sum_j w*feat
    const int idx = r * 256 + tid;
    const int g = idx >> 7, d = idx & 127;
    x1t[g][d] = w16[g * 4] * feat[g * 4][d] + w16[g * 4 + 1] * feat[g * 4 + 1][d]
              + w16[g * 4 + 2] * feat[g * 4 + 2][d] + w16[g * 4 + 3] * feat[g * 4 + 3][d];
  }
  __syncthreads();
  {   // layer-1 GEMV
    const int e = tid & 127, gh = tid >> 7;
    float a0 = 0.f, a1 = 0.f;
#pragma unroll 8
    for (int d = 0; d < 128; ++d) {
      const float wv = WT1[d * 128 + e];
      a0 += x1t[gh * 2][d] * wv;
      a1 += x1t[gh * 2 + 1][d] * wv;
    }
    h1[gh * 2][e]     = a0 * 0.25f + b1[e];
    h1[gh * 2 + 1][e] = a1 * 0.25f + b1[e];
  }
  __syncthreads();
  {   // layer-2 GEMV + output
    const int e = tid & 127, gh = tid >> 7;
    float a0 = 0.f, a1 = 0.f;
#pragma unroll 8
    for (int d = 0; d < 128; ++d) {
      const float wv = WT2[d * 128 + e];
      a0 += h1[gh * 2][d] * wv;
      a1 += h1[gh * 2 + 1][d] * wv;
    }
    const float bb = b2[e];
    out[((size_t)b * 128 + e) * 4 + gh * 2]     = a0 + bb;
    out[((size_t)b * 128 + e) * 4 + gh * 2 + 1] = a1 + bb;
  }
}

// ---------------------------------------------------------------------------
extern "C" void kernel_launch(void* const* d_in, const int* in_sizes, int n_in,
                              void* d_out, int out_size, void* d_ws, size_t ws_size,
                              hipStream_t stream) {
  (void)in_sizes; (void)n_in; (void)out_size; (void)ws_size;
  const float* x       = (const float*)d_in[0];
  const int*   lengths = (const int*)  d_in[1];
  const float* W0  = (const float*)d_in[2];
  const float* as0 = (const float*)d_in[3];
  const float* ad0 = (const float*)d_in[4];
  const float* b0  = (const float*)d_in[5];
  const float* W1  = (const float*)d_in[6];
  const float* as1 = (const float*)d_in[7];
  const float* ad1 = (const float*)d_in[8];
  const float* b1  = (const float*)d_in[9];
  const float* W2  = (const float*)d_in[10];
  const float* as2 = (const float*)d_in[11];
  const float* ad2 = (const float*)d_in[12];
  const float* b2  = (const float*)d_in[13];
  float* ws  = (float*)d_ws;
  float* out = (float*)d_out;

  setup_kernel<<<48, 256, 0, stream>>>(W0, as0, ad0, W1, as1, ad1, W2, as2, ad2, ws);
  l0_kernel<<<1024, 256, 0, stream>>>(x, lengths, ws + OFF_U, ws + OFF_XT);
  l12_kernel<<<64, 256, 0, stream>>>(ws + OFF_XT, lengths, ws, b0, b1, b2, out);
}

// Round 10
// 96.764 us; speedup vs baseline: 1.0271x; 1.0271x over previous
//
#include <hip/hip_runtime.h>

#define NEG_SLOPE 0.2f

// ws float offsets: U [0,768), WT [1024,50176), then spt | w | xt (host-computed)
#define OFF_U   0
#define OFF_WT  1024

__device__ __forceinline__ float lrelu(float z) { return z >= 0.f ? z : NEG_SLOPE * z; }

// ---------------------------------------------------------------------------
// Setup [verbatim r6]: WT transposes + u vectors.
__global__ __launch_bounds__(256) void setup_kernel(
    const float* __restrict__ W0, const float* __restrict__ as0, const float* __restrict__ ad0,
    const float* __restrict__ W1, const float* __restrict__ as1, const float* __restrict__ ad1,
    const float* __restrict__ W2, const float* __restrict__ as2, const float* __restrict__ ad2,
    float* __restrict__ ws) {
  __shared__ float tile[8][132];
  const int bid = blockIdx.x;
  const int l = bid >> 4, sub = bid & 15;
  const int tid = threadIdx.x;
  const float* W = (l == 0) ? W0 : (l == 1) ? W1 : W2;
  float* WT = ws + OFF_WT + l * 16384;
  const int e0 = sub * 8;

#pragma unroll
  for (int i = 0; i < 4; ++i) {
    const int idx = i * 256 + tid;
    tile[idx >> 7][idx & 127] = W[(e0 + (idx >> 7)) * 128 + (idx & 127)];
  }
  __syncthreads();
#pragma unroll
  for (int i = 0; i < 4; ++i) {
    const int idx = i * 256 + tid;
    const int d = idx >> 3, j = idx & 7;
    WT[d * 128 + e0 + j] = tile[j][d];
  }
  if (sub == 0) {
    const float* av = (tid < 128) ? ((l == 0) ? as0 : (l == 1) ? as1 : as2)
                                  : ((l == 0) ? ad0 : (l == 1) ? ad1 : ad2);
    const int d = tid & 127;
    float acc = 0.f;
#pragma unroll 8
    for (int e = 0; e < 128; ++e) acc += av[e] * W[e * 128 + d];
    ws[OFF_U + l * 256 + tid] = acc;
  }
}

// ---------------------------------------------------------------------------
// k1: s,t partial dots. Block (b, dc) streams R=128/DC rows CONTIGUOUSLY.
// ZERO LDS. u from scalar loads (uniform addresses). Writes [b*DC+dc][2][4096].
template<int R>
__global__ __launch_bounds__(256, 4) void st_kernel(
    const float* __restrict__ x, const float* __restrict__ u0,
    float* __restrict__ spt) {
  const int t   = threadIdx.x;
  const int bid = blockIdx.x;
  constexpr int DC = 128 / R;
  const int b  = bid / DC, dc = bid % DC;
  const float* base = x + ((size_t)(b * 128 + dc * R)) * 4096;

  float us_r[R], ud_r[R];
#pragma unroll
  for (int r = 0; r < R; ++r) {
    us_r[r] = u0[dc * R + r];
    ud_r[r] = u0[128 + dc * R + r];
  }

  float4 as[4], at[4];
#pragma unroll
  for (int q = 0; q < 4; ++q) {
    as[q] = make_float4(0.f, 0.f, 0.f, 0.f);
    at[q] = make_float4(0.f, 0.f, 0.f, 0.f);
  }

#pragma unroll
  for (int r = 0; r < R; ++r) {
    const float us = us_r[r], ud = ud_r[r];
#pragma unroll
    for (int q = 0; q < 4; ++q) {
      const float4 v = *(const float4*)(base + ((size_t)(r * 4 + q)) * 1024 + t * 4);
      as[q].x += v.x * us; as[q].y += v.y * us; as[q].z += v.z * us; as[q].w += v.w * us;
      at[q].x += v.x * ud; at[q].y += v.y * ud; at[q].z += v.z * ud; at[q].w += v.w * ud;
    }
  }

  float* o0 = spt + ((size_t)bid * 2) * 4096;
#pragma unroll
  for (int q = 0; q < 4; ++q) {
    *(float4*)(o0 + q * 1024 + t * 4)        = as[q];
    *(float4*)(o0 + 4096 + q * 1024 + t * 4) = at[q];
  }
}

// ---------------------------------------------------------------------------
// k2: reduce DC partials -> s,t per patch; r2-verified attention; w out.
template<int DC>
__global__ __launch_bounds__(256) void attn_kernel(
    const float* __restrict__ spt, const int* __restrict__ lengths,
    float* __restrict__ wout) {
  __shared__ float sA[256], tA[256], am1[256], asf[256], ap1[256];
  const int t = threadIdx.x, bid = blockIdx.x;
  const int b = bid >> 4, p = bid & 15;

  float sa = 0.f, ta = 0.f;
#pragma unroll
  for (int dc = 0; dc < DC; ++dc) {
    const float* row = spt + ((size_t)(b * DC + dc) * 2) * 4096 + p * 256;
    sa += row[t];
    ta += row[4096 + t];
  }
  sA[t] = sa; tA[t] = ta;
  __syncthreads();

  const int len = lengths[b];
  {
    const int j = t;
    const float tj = tA[j];
    const float ls = lrelu(sA[j] + tj);
    const float lm = (j > 0)   ? lrelu(sA[j - 1] + tj) : -1e30f;
    const float lp = (j < 255) ? lrelu(sA[j + 1] + tj) : -1e30f;
    const float mx = fmaxf(ls, fmaxf(lm, lp));
    const float em = (j > 0)   ? __expf(lm - mx) : 0.f;
    const float es = __expf(ls - mx);
    const float ep = (j < 255) ? __expf(lp - mx) : 0.f;
    const float vj = ((p * 256 + j) < len) ? 1.f : 0.f;
    const float sc = vj / (em + es + ep);
    am1[j] = em * sc; asf[j] = es * sc; ap1[j] = ep * sc;
  }
  __syncthreads();
  {
    const int n = t;
    float w = asf[n];
    if (n < 255) w += am1[n + 1];
    if (n > 0)   w += ap1[n - 1];
    wout[(size_t)b * 4096 + p * 256 + n] = w;
  }
}

// ---------------------------------------------------------------------------
// k3: weighted column-sum. Block (b, c3) streams 8 rows CONTIGUOUSLY.
// w preloaded to 16 registers; loop has only loads + FMA + ds_write.
// FIX vs r9: reduction index map was swapped; correct is q = p>>2, u = p&3.
__global__ __launch_bounds__(256, 4) void colsum_kernel(
    const float* __restrict__ x, const float* __restrict__ wv,
    float* __restrict__ xt) {
  __shared__ float part[32 * 256];
  const int t = threadIdx.x, bid = blockIdx.x;
  const int b = bid >> 4, c3 = bid & 15;
  const float* base = x + ((size_t)(b * 128 + c3 * 8)) * 4096;

  float4 w4[4];
#pragma unroll
  for (int q = 0; q < 4; ++q)
    w4[q] = *(const float4*)(wv + (size_t)b * 4096 + q * 1024 + t * 4);

#pragma unroll
  for (int r = 0; r < 8; ++r) {
#pragma unroll
    for (int q = 0; q < 4; ++q) {
      const float4 v = *(const float4*)(base + ((size_t)(r * 4 + q)) * 1024 + t * 4);
      part[(r * 4 + q) * 256 + t] =
          v.x * w4[q].x + v.y * w4[q].y + v.z * w4[q].z + v.w * w4[q].w;
    }
  }
  __syncthreads();

  // output (patch p, row r): sum part[(r*4+q)*256 + t] over t in [u*64, u*64+64),
  // where q = p>>2 selects the 1024-col quarter, u = p&3 the 256-col slice.
  const int out = t >> 1, half = t & 1;
  const int p = out >> 3, r = out & 7, q = p >> 2, u = p & 3;
  float acc = 0.f;
#pragma unroll
  for (int j = 0; j < 32; ++j) {
    const int jj = (j + t) & 31;                       // bank spread (2-way max)
    acc += part[(r * 4 + q) * 256 + u * 64 + half * 32 + jj];
  }
  acc += __shfl_xor(acc, 1);
  if (half == 0)
    xt[((size_t)b * 16 + p) * 128 + c3 * 8 + r] = acc;
}

// ---------------------------------------------------------------------------
// l12 [verbatim r8]: feat GEMV (W0) + layer1 + layer2. One block per b.
__global__ __launch_bounds__(256) void l12_kernel(
    const float* __restrict__ xtp, const int* __restrict__ lengths,
    const float* __restrict__ ws,
    const float* __restrict__ b0, const float* __restrict__ b1,
    const float* __restrict__ b2, float* __restrict__ out) {
  __shared__ float xt[16][128];
  __shared__ float pr[2][16][128];
  __shared__ float feat[16][128];
  __shared__ float spt[2][16][16];
  __shared__ float s1[16], t1[16], am[16], asf[16], ap[16], w16[16];
  __shared__ float rc_sh[16];
  __shared__ float x1t[4][128];
  __shared__ float h1[4][128];

  const int tid = threadIdx.x;
  const int b = blockIdx.x;
  const float* WT0 = ws + OFF_WT;
  const float* WT1 = ws + OFF_WT + 16384;
  const float* WT2 = ws + OFF_WT + 32768;
  const float* u1  = ws + OFF_U + 256;
  const int len = lengths[b];

#pragma unroll
  for (int i = 0; i < 8; ++i) {
    const int pp = i * 2 + (tid >> 7);
    const int d = tid & 127;
    xt[pp][d] = xtp[((size_t)b * 16 + pp) * 128 + d];
  }
  if (tid < 16) {
    const int rem = len - tid * 256;
    const int cnt = rem < 0 ? 0 : (rem > 256 ? 256 : rem);
    rc_sh[tid] = cnt > 0 ? 1.f / (float)cnt : 0.f;
  }
  __syncthreads();

  {
    const int e = tid & 127, dhalf = tid >> 7;
    float acc[16];
#pragma unroll
    for (int q = 0; q < 16; ++q) acc[q] = 0.f;
#pragma unroll 4
    for (int k = 0; k < 64; ++k) {
      const int d = dhalf * 64 + k;
      const float wv = WT0[d * 128 + e];
#pragma unroll
      for (int q = 0; q < 16; ++q) acc[q] += xt[q][d] * wv;
    }
#pragma unroll
    for (int q = 0; q < 16; ++q) pr[dhalf][q][e] = acc[q];
  }
  __syncthreads();
  {
    const int e = tid & 127, ph = tid >> 7;
    const float bb = b0[e];
#pragma unroll
    for (int i = 0; i < 8; ++i) {
      const int q = ph * 8 + i;
      const float rcv = rc_sh[q];
      const float f = (pr[0][q][e] + pr[1][q][e]) * rcv + bb;
      feat[q][e] = (rcv == 0.f) ? 0.f : f;
    }
  }
  __syncthreads();

  {
    const int q = tid >> 4, sl = tid & 15;
    float ps = 0.f, pt = 0.f;
#pragma unroll
    for (int k = 0; k < 8; ++k) {
      const int e = sl * 8 + k;
      const float f = feat[q][e];
      ps += f * u1[e];
      pt += f * u1[128 + e];
    }
    spt[0][q][sl] = ps; spt[1][q][sl] = pt;
  }
  __syncthreads();
  if (tid < 32) {
    const int q = tid >> 4, pp = tid & 15;
    float a = 0.f;
#pragma unroll
    for (int i = 0; i < 16; ++i) a += spt[q][pp][i];
    if (q == 0) s1[pp] = a; else t1[pp] = a;
  }
  __syncthreads();
  if (tid < 16) {
    const int jl = tid & 3;
    const float tj = t1[tid];
    const float ls = lrelu(s1[tid] + tj);
    const float lm = (jl > 0) ? lrelu(s1[tid - 1] + tj) : -1e30f;
    const float lp = (jl < 3) ? lrelu(s1[tid + 1] + tj) : -1e30f;
    const float mx = fmaxf(ls, fmaxf(lm, lp));
    const float em = (jl > 0) ? __expf(lm - mx) : 0.f;
    const float es = __expf(ls - mx);
    const float ep = (jl < 3) ? __expf(lp - mx) : 0.f;
    const float sc = 1.f / (em + es + ep);
    am[tid] = em * sc; asf[tid] = es * sc; ap[tid] = ep * sc;
  }
  __syncthreads();
  if (tid < 16) {
    const int jl = tid & 3;
    float w = asf[tid];
    if (jl < 3) w += am[tid + 1];
    if (jl > 0) w += ap[tid - 1];
    w16[tid] = w;
  }
  __syncthreads();
#pragma unroll
  for (int r = 0; r < 2; ++r) {
    const int idx = r * 256 + tid;
    const int g = idx >> 7, d = idx & 127;
    x1t[g][d] = w16[g * 4] * feat[g * 4][d] + w16[g * 4 + 1] * feat[g * 4 + 1][d]
              + w16[g * 4 + 2] * feat[g * 4 + 2][d] + w16[g * 4 + 3] * feat[g * 4 + 3][d];
  }
  __syncthreads();
  {
    const int e = tid & 127, gh = tid >> 7;
    float a0 = 0.f, a1 = 0.f;
#pragma unroll 8
    for (int d = 0; d < 128; ++d) {
      const float wv = WT1[d * 128 + e];
      a0 += x1t[gh * 2][d] * wv;
      a1 += x1t[gh * 2 + 1][d] * wv;
    }
    h1[gh * 2][e]     = a0 * 0.25f + b1[e];
    h1[gh * 2 + 1][e] = a1 * 0.25f + b1[e];
  }
  __syncthreads();
  {
    const int e = tid & 127, gh = tid >> 7;
    float a0 = 0.f, a1 = 0.f;
#pragma unroll 8
    for (int d = 0; d < 128; ++d) {
      const float wv = WT2[d * 128 + e];
      a0 += h1[gh * 2][d] * wv;
      a1 += h1[gh * 2 + 1][d] * wv;
    }
    const float bb = b2[e];
    out[((size_t)b * 128 + e) * 4 + gh * 2]     = a0 + bb;
    out[((size_t)b * 128 + e) * 4 + gh * 2 + 1] = a1 + bb;
  }
}

// ---------------------------------------------------------------------------
extern "C" void kernel_launch(void* const* d_in, const int* in_sizes, int n_in,
                              void* d_out, int out_size, void* d_ws, size_t ws_size,
                              hipStream_t stream) {
  (void)in_sizes; (void)n_in; (void)out_size;
  const float* x       = (const float*)d_in[0];
  const int*   lengths = (const int*)  d_in[1];
  const float* W0  = (const float*)d_in[2];
  const float* as0 = (const float*)d_in[3];
  const float* ad0 = (const float*)d_in[4];
  const float* b0  = (const float*)d_in[5];
  const float* W1  = (const float*)d_in[6];
  const float* as1 = (const float*)d_in[7];
  const float* ad1 = (const float*)d_in[8];
  const float* b1  = (const float*)d_in[9];
  const float* W2  = (const float*)d_in[10];
  const float* as2 = (const float*)d_in[11];
  const float* ad2 = (const float*)d_in[12];
  const float* b2  = (const float*)d_in[13];
  float* ws  = (float*)d_ws;
  float* out = (float*)d_out;

  // ws partition (floats): [U 768][WT 49152 @1024][spt][w 262144][xt 131072]
  const size_t need16 = (size_t)(50176 + 64 * 16 * 2 * 4096 + 262144 + 131072) * 4;
  const bool big = ws_size >= need16;
  const size_t sptN = big ? (size_t)64 * 16 * 2 * 4096 : (size_t)64 * 4 * 2 * 4096;
  float* spt  = ws + 50176;
  float* wbuf = spt + sptN;
  float* xt   = wbuf + 262144;

  setup_kernel<<<48, 256, 0, stream>>>(W0, as0, ad0, W1, as1, ad1, W2, as2, ad2, ws);
  if (big) {
    st_kernel<8><<<1024, 256, 0, stream>>>(x, ws + OFF_U, spt);
    attn_kernel<16><<<1024, 256, 0, stream>>>(spt, lengths, wbuf);
  } else {
    st_kernel<32><<<256, 256, 0, stream>>>(x, ws + OFF_U, spt);
    attn_kernel<4><<<1024, 256, 0, stream>>>(spt, lengths, wbuf);
  }
  colsum_kernel<<<1024, 256, 0, stream>>>(x, wbuf, xt);
  l12_kernel<<<64, 256, 0, stream>>>(xt, lengths, ws, b0, b1, b2, out);
}

// Round 11
// 65.258 us; speedup vs baseline: 1.5229x; 1.4828x over previous
//
#include <hip/hip_runtime.h>

#define NEG_SLOPE 0.2f

// ws layout (in floats)
#define OFF_U   0        // 3 layers * 256 (u_src[128] | u_dst[128])
#define OFF_WT  1024     // 3 * 16384 (W transposed: WT[d*128+e] = W[e*128+d])
#define OFF_X1  50176    // 64*128*16  layer-0 output, layout [b][d][16]

__device__ __forceinline__ float lrelu(float z) { return z >= 0.f ? z : NEG_SLOPE * z; }

__device__ __forceinline__ unsigned short f2bf(float f) {   // RTNE float->bf16
  unsigned u = __float_as_uint(f);
  u += 0x7FFFu + ((u >> 16) & 1u);
  return (unsigned short)(u >> 16);
}

// ---------------------------------------------------------------------------
// Setup [verbatim r3]: WT transposes + u vectors.
__global__ __launch_bounds__(256) void setup_kernel(
    const float* __restrict__ W0, const float* __restrict__ as0, const float* __restrict__ ad0,
    const float* __restrict__ W1, const float* __restrict__ as1, const float* __restrict__ ad1,
    const float* __restrict__ W2, const float* __restrict__ as2, const float* __restrict__ ad2,
    float* __restrict__ ws) {
  __shared__ float tile[8][132];
  const int bid = blockIdx.x;
  const int l = bid >> 4, sub = bid & 15;
  const int tid = threadIdx.x;
  const float* W = (l == 0) ? W0 : (l == 1) ? W1 : W2;
  float* WT = ws + OFF_WT + l * 16384;
  const int e0 = sub * 8;

#pragma unroll
  for (int i = 0; i < 4; ++i) {     // read 8 rows of W, coalesced
    const int idx = i * 256 + tid;
    tile[idx >> 7][idx & 127] = W[(e0 + (idx >> 7)) * 128 + (idx & 127)];
  }
  __syncthreads();
#pragma unroll
  for (int i = 0; i < 4; ++i) {     // write transposed
    const int idx = i * 256 + tid;
    const int d = idx >> 3, j = idx & 7;
    WT[d * 128 + e0 + j] = tile[j][d];
  }
  if (sub == 0) {
    const float* av = (tid < 128) ? ((l == 0) ? as0 : (l == 1) ? as1 : as2)
                                  : ((l == 0) ? ad0 : (l == 1) ? ad1 : ad2);
    const int d = tid & 127;
    float acc = 0.f;
#pragma unroll 8
    for (int e = 0; e < 128; ++e) acc += av[e] * W[e * 128 + d];
    ws[OFF_U + l * 256 + tid] = acc;
  }
}

// ---------------------------------------------------------------------------
// Layer 0 [r3 verbatim EXCEPT: u-values hoisted from LDS into registers
// before the staging loop -> the hot loop has ZERO LDS reads].
// One block per (b, patch p of 256 nodes). block 512 = 8 waves.
// LDS ~77.8 KB -> 2 blocks/CU; launch_bounds caps VGPR at 128.
__global__ __launch_bounds__(512, 4) void l0_kernel(
    const float* __restrict__ x, const int* __restrict__ lengths,
    const float* __restrict__ uvec, const float* __restrict__ WT0,
    const float* __restrict__ b0, float* __restrict__ x1) {
  __shared__ unsigned short xs[128 * 264];   // bf16 x[d][n], row stride 264
  __shared__ float red[2048];                // multi-purpose scratch (8 KB)
  __shared__ float sA[256], tA[256];

  const int tid  = threadIdx.x;
  const int bid  = blockIdx.x;
  const int b    = bid >> 4;
  const int p    = bid & 15;
  const int lane = tid & 63;
  const int wave = __builtin_amdgcn_readfirstlane(tid >> 6);

  // ---- u values for this thread's 16 d-rows: registers, not LDS ----
  float us_r[16], ud_r[16];
#pragma unroll
  for (int it = 0; it < 16; ++it) {
    us_r[it] = uvec[it * 8 + wave];
    ud_r[it] = uvec[128 + it * 8 + wave];
  }

  // ---- stage x patch into LDS (bf16), fusing fp32 s,t partial dots.
  //      Hot loop: global_load + fmac + pack + ds_write. No LDS reads. ----
  const float* xb = x + ((size_t)b * 128) * 4096 + p * 256;
  float s0 = 0.f, s1 = 0.f, s2 = 0.f, s3 = 0.f;
  float t0 = 0.f, t1 = 0.f, t2 = 0.f, t3 = 0.f;
#pragma unroll 8
  for (int it = 0; it < 16; ++it) {
    const int d = it * 8 + wave;
    const float4 v = *(const float4*)(xb + (size_t)d * 4096 + lane * 4);
    const float us = us_r[it];
    const float ud = ud_r[it];
    s0 += v.x * us; s1 += v.y * us; s2 += v.z * us; s3 += v.w * us;
    t0 += v.x * ud; t1 += v.y * ud; t2 += v.z * ud; t3 += v.w * ud;
    ushort4 pk;
    pk.x = f2bf(v.x); pk.y = f2bf(v.y); pk.z = f2bf(v.z); pk.w = f2bf(v.w);
    *(ushort4*)(&xs[d * 264 + lane * 4]) = pk;
  }

  // ---- s,t reduction: 8 wave-partials -> 4 in-place, then 4 -> 1 [r3] ----
  const int n4 = lane * 4;
  if (wave >= 4) *(float4*)(&red[(wave - 4) * 256 + n4])   = make_float4(s0, s1, s2, s3);
  else           *(float4*)(&red[1024 + wave * 256 + n4])  = make_float4(t0, t1, t2, t3);
  __syncthreads();
  if (wave < 4) {
    float4 r = *(float4*)(&red[wave * 256 + n4]);
    r.x += s0; r.y += s1; r.z += s2; r.w += s3;
    *(float4*)(&red[wave * 256 + n4]) = r;
  } else {
    float4 r = *(float4*)(&red[1024 + (wave - 4) * 256 + n4]);
    r.x += t0; r.y += t1; r.z += t2; r.w += t3;
    *(float4*)(&red[1024 + (wave - 4) * 256 + n4]) = r;
  }
  __syncthreads();
  if (tid < 256) {
    sA[tid] = red[tid] + red[256 + tid] + red[512 + tid] + red[768 + tid];
  } else {
    const int n = tid - 256;
    tA[n] = red[1024 + n] + red[1280 + n] + red[1536 + n] + red[1792 + n];
  }
  __syncthreads();

  const int len = lengths[b];

  if (tid < 256) {   // attention per dst j; fold dst validity [r3]
    const int j = tid;
    const float tj = tA[j];
    const float ls = lrelu(sA[j] + tj);
    const float lm = (j > 0)   ? lrelu(sA[j - 1] + tj) : -1e30f;
    const float lp = (j < 255) ? lrelu(sA[j + 1] + tj) : -1e30f;
    const float mx = fmaxf(ls, fmaxf(lm, lp));
    const float em = (j > 0)   ? __expf(lm - mx) : 0.f;
    const float es = __expf(ls - mx);
    const float ep = (j < 255) ? __expf(lp - mx) : 0.f;
    const float vj = ((p * 256 + j) < len) ? 1.f : 0.f;
    const float sc = vj / (em + es + ep);
    red[j] = em * sc;          // am1
    red[256 + j] = es * sc;    // aself
    red[512 + j] = ep * sc;    // ap1
  }
  __syncthreads();

  if (tid < 256) {   // source weights w[n] [r3]
    const int n = tid;
    float w = red[256 + n];
    if (n < 255) w += red[n + 1];
    if (n > 0)   w += red[512 + n - 1];
    red[768 + n] = w;          // w_sh
  }
  __syncthreads();

  {   // x~[d] partials: thread (d, q) sums quarter q; staggered rotation [r3]
    const int d = tid >> 2, q = tid & 3;
    float acc = 0.f;
#pragma unroll 8
    for (int j = 0; j < 32; ++j) {
      const int jj = (j + d + q * 8) & 31;
      const int n  = q * 64 + jj * 2;
      const unsigned pair = *(const unsigned*)(&xs[d * 264 + n]);
      const float f0 = __uint_as_float(pair << 16);
      const float f1 = __uint_as_float(pair & 0xFFFF0000u);
      const float2 w2 = *(const float2*)(&red[768 + n]);
      acc += w2.x * f0 + w2.y * f1;
    }
    red[1024 + tid] = acc;
  }
  __syncthreads();

  if (tid < 128) {   // combine 4 quarters -> xtp (reuse sA) [r3]
    const float4 r = *(const float4*)(&red[1024 + tid * 4]);
    sA[tid] = r.x + r.y + r.z + r.w;
  }
  __syncthreads();

  {   // feat[e] partials over d-slices via WT0 (coalesced) [r3]
    const int e = tid & 127, eh = tid >> 7;
    float acc = 0.f;
#pragma unroll 8
    for (int k = 0; k < 32; ++k) {
      const int d = eh * 32 + k;
      acc += sA[d] * WT0[d * 128 + e];
    }
    red[eh * 128 + e] = acc;
  }
  __syncthreads();

  if (tid < 128) {   // [r3]
    const int e = tid;
    const int rem = len - p * 256;
    const int cnt = rem < 0 ? 0 : (rem > 256 ? 256 : rem);
    float o = 0.f;
    if (cnt > 0)
      o = (red[e] + red[128 + e] + red[256 + e] + red[384 + e]) / (float)cnt + b0[e];
    x1[(size_t)(b * 128 + e) * 16 + p] = o;    // layout [b][d][16]
  }
}

// ---------------------------------------------------------------------------
// Fused layers 1+2 [verbatim r3]: one block per (b, p) p in [0,4); block 128.
__global__ __launch_bounds__(128) void l12_kernel(
    const float* __restrict__ x1, const float* __restrict__ u1,
    const float* __restrict__ WT1, const float* __restrict__ b1,
    const float* __restrict__ WT2, const float* __restrict__ b2,
    float* __restrict__ out) {
  __shared__ float xg[128][4];
  __shared__ float stp[8][128];
  __shared__ float sA[4], tA[4], am[4], asf[4], ap[4], w4[4];
  __shared__ float x2l[128];

  const int tid = threadIdx.x;
  const int bid = blockIdx.x;
  const int b = bid >> 2, p = bid & 3;

  const int d = tid;
  const float4 v = *(const float4*)(x1 + (size_t)(b * 128 + d) * 16 + p * 4);
  *(float4*)(&xg[d][0]) = v;
  const float us = u1[d], ud = u1[128 + d];
  stp[0][d] = v.x * us; stp[1][d] = v.y * us; stp[2][d] = v.z * us; stp[3][d] = v.w * us;
  stp[4][d] = v.x * ud; stp[5][d] = v.y * ud; stp[6][d] = v.z * ud; stp[7][d] = v.w * ud;
  __syncthreads();

  if (tid < 8) {
    float acc = 0.f;
    for (int k = 0; k < 128; ++k) acc += stp[tid][k];
    if (tid < 4) sA[tid] = acc; else tA[tid - 4] = acc;
  }
  __syncthreads();

  if (tid < 4) {
    const int j = tid;
    const float tj = tA[j];
    const float ls = lrelu(sA[j] + tj);
    const float lm = (j > 0) ? lrelu(sA[j - 1] + tj) : -1e30f;
    const float lp = (j < 3) ? lrelu(sA[j + 1] + tj) : -1e30f;
    const float mx = fmaxf(ls, fmaxf(lm, lp));
    const float em = (j > 0) ? __expf(lm - mx) : 0.f;
    const float es = __expf(ls - mx);
    const float ep = (j < 3) ? __expf(lp - mx) : 0.f;
    const float sc = 1.f / (em + es + ep);
    am[j] = em * sc; asf[j] = es * sc; ap[j] = ep * sc;
  }
  __syncthreads();

  if (tid < 4) {
    const int n = tid;
    float w = asf[n];
    if (n < 3) w += am[n + 1];
    if (n > 0) w += ap[n - 1];
    w4[n] = w;
  }
  __syncthreads();

  {   // layer-1 feat[e]
    const float w0 = w4[0], w1 = w4[1], w2 = w4[2], w3 = w4[3];
    float acc = 0.f;
#pragma unroll 8
    for (int dd = 0; dd < 128; ++dd) {
      const float xt = w0 * xg[dd][0] + w1 * xg[dd][1] + w2 * xg[dd][2] + w3 * xg[dd][3];
      acc += xt * WT1[dd * 128 + tid];
    }
    x2l[tid] = acc * 0.25f + b1[tid];
  }
  __syncthreads();

  {   // layer 2: single node, self loop -> alpha=1
    float acc = 0.f;
#pragma unroll 8
    for (int dd = 0; dd < 128; ++dd) acc += x2l[dd] * WT2[dd * 128 + tid];
    out[(size_t)(b * 128 + tid) * 4 + p] = acc + b2[tid];
  }
}

// ---------------------------------------------------------------------------
extern "C" void kernel_launch(void* const* d_in, const int* in_sizes, int n_in,
                              void* d_out, int out_size, void* d_ws, size_t ws_size,
                              hipStream_t stream) {
  (void)in_sizes; (void)n_in; (void)out_size; (void)ws_size;
  const float* x       = (const float*)d_in[0];
  const int*   lengths = (const int*)  d_in[1];
  const float* W0  = (const float*)d_in[2];
  const float* as0 = (const float*)d_in[3];
  const float* ad0 = (const float*)d_in[4];
  const float* b0  = (const float*)d_in[5];
  const float* W1  = (const float*)d_in[6];
  const float* as1 = (const float*)d_in[7];
  const float* ad1 = (const float*)d_in[8];
  const float* b1  = (const float*)d_in[9];
  const float* W2  = (const float*)d_in[10];
  const float* as2 = (const float*)d_in[11];
  const float* ad2 = (const float*)d_in[12];
  const float* b2  = (const float*)d_in[13];
  float* ws  = (float*)d_ws;
  float* out = (float*)d_out;

  setup_kernel<<<48, 256, 0, stream>>>(W0, as0, ad0, W1, as1, ad1, W2, as2, ad2, ws);
  l0_kernel<<<1024, 512, 0, stream>>>(x, lengths, ws + OFF_U, ws + OFF_WT, b0, ws + OFF_X1);
  l12_kernel<<<256, 128, 0, stream>>>(ws + OFF_X1, ws + OFF_U + 256,
                                      ws + OFF_WT + 16384, b1,
                                      ws + OFF_WT + 32768, b2, out);
}